// Round 16
// baseline (654.194 us; speedup 1.0000x reference)
//
#include <hip/hip_runtime.h>
#include <math.h>

// ---------------------------------------------------------------------------
// MPNN (NNConv+GRU x3, Set2Set x3, readout).
// R26: straggler rebalance on R25. The bias+root extra iteration (formerly
// all on split 0, making it ~11% longer) is split: bias chunk (kc=64,
// edge-loop) -> split 1 as a SINGLE-phase extra (ph=0); root chunk (kc=65,
// one row-load) -> split 2 (ph=1 only). Splits 0,3 run no extra. Total MFMA
// unchanged; per-split overhang ~halved. Everything else identical to R25.
// ---------------------------------------------------------------------------

typedef _Float16 f16x8 __attribute__((ext_vector_type(8)));
typedef _Float16 h2 __attribute__((ext_vector_type(2)));
typedef float f32x4 __attribute__((ext_vector_type(4)));

#define BFRAG_TOTAL (66 * 4 * 4 * 64 * 8)  // 540672 halves per array
#define GFRAG_TOTAL (4 * 16 * 64 * 8)      // 32768 halves per array
#define PAIRS_CAP 40064                    // >= (E+N)/2, multiple of 128
#define PMAX 152                           // max pairs per 64-node block (LDS)
#define SPLITK 4
#define ITERS 8                            // 4-k chunks per split (32 k total)
#define NB_BS 66
#define NB_GS 16
#define NB_H1 (PAIRS_CAP / 128)            // 313

#if __has_builtin(__builtin_amdgcn_fdot2)
#define FDOT2(a, b, c) __builtin_amdgcn_fdot2((a), (b), (c), false)
#else
__device__ __forceinline__ float FDOT2(h2 a, h2 b, float c) {
  return c + (float)a[0] * (float)b[0] + (float)a[1] * (float)b[1];
}
#endif

// merged: graph segment pointers (from sorted batch) + degree count
__global__ void k_gc(const int* __restrict__ batch, int* __restrict__ gptr,
                     const int* __restrict__ eidx, int* __restrict__ cnt,
                     int N, int E, int B) {
  int i = blockIdx.x * 256 + threadIdx.x;
  if (i < N) {
    int b = batch[i];
    int bp = (i == 0) ? -1 : batch[i - 1];
    for (int g = bp + 1; g <= b; ++g) gptr[g] = i;
    if (i == N - 1) {
      for (int g = b + 1; g <= B; ++g) gptr[g] = N;
    }
  }
  if (i < E) atomicAdd(&cnt[eidx[E + i]], 1);
}

// segment-per-thread scan of EVEN-PADDED degrees -> dptr2 (2 barriers)
__global__ __launch_bounds__(1024) void k_scan(const int* __restrict__ cnt,
                                               int* __restrict__ dptr2, int N) {
  __shared__ int wsum[16];
  const int t = threadIdx.x, lane = t & 63, wid = t >> 6;
  const int per = (N + 1023) >> 10;
  int beg = t * per;
  int end = beg + per;
  if (beg > N) beg = N;
  if (end > N) end = N;
  int s = 0;
  for (int i = beg; i < end; ++i) s += (cnt[i] + 1) & ~1;
  int x = s;
#pragma unroll
  for (int d = 1; d < 64; d <<= 1) {
    int u = __shfl_up(x, d, 64);
    if (lane >= d) x += u;
  }
  if (lane == 63) wsum[wid] = x;
  __syncthreads();
  if (wid == 0) {
    int y = (lane < 16) ? wsum[lane] : 0;
#pragma unroll
    for (int d = 1; d < 16; d <<= 1) {
      int u = __shfl_up(y, d, 64);
      if (lane >= d) y += u;
    }
    if (lane < 16) wsum[lane] = y;
  }
  __syncthreads();
  int run = (x - s) + (wid > 0 ? wsum[wid - 1] : 0);  // exclusive prefix
  for (int i = beg; i < end; ++i) {
    run += (cnt[i] + 1) & ~1;
    dptr2[i + 1] = run;
  }
  if (t == 0) dptr2[0] = 0;
}

// fill CSR + write odd-degree pad slots (replaces srcs_s/eord memsets)
__global__ void k_fill(const int* __restrict__ eidx, const int* __restrict__ dptr2,
                       const int* __restrict__ cnt, int* __restrict__ fill,
                       int* __restrict__ srcs_s, int* __restrict__ eord, int E,
                       int N) {
  int i = blockIdx.x * 256 + threadIdx.x;
  if (i < E) {
    int d = eidx[E + i];
    int pos = dptr2[d] + atomicAdd(&fill[d], 1);
    srcs_s[pos] = eidx[i];
    eord[pos] = i;
  }
  if (i < N) {
    int dg = cnt[i];
    if (dg & 1) {
      int pos = dptr2[i] + dg;
      srcs_s[pos] = 0;
      eord[pos] = -1;
    }
  }
}

// ---- merged pre-pass: [0,NB_BS) bsplit | [..+NB_GS) gsplit |
//      [..+NB_H1) h1t | rest lin0 -----------------------------------------
__global__ __launch_bounds__(256) void k_prep(
    // bsplit
    const float* __restrict__ nn2_w, const float* __restrict__ nn2_b,
    const float* __restrict__ root_w, _Float16* __restrict__ Bh,
    _Float16* __restrict__ Bl,
    // gsplit
    const float* __restrict__ gw_ih, const float* __restrict__ gw_hh,
    _Float16* __restrict__ Gh, _Float16* __restrict__ Gl,
    // h1t
    const float* __restrict__ eattr, const int* __restrict__ eord,
    const int* __restrict__ eidx, const int* __restrict__ cnt,
    const int* __restrict__ dptr2, const float* __restrict__ nn1_w,
    const float* __restrict__ nn1_b, f16x8* __restrict__ hp, int E,
    // lin0
    const float* __restrict__ x, const float* __restrict__ lin0_w,
    const float* __restrict__ lin0_b, float* __restrict__ outn, int N) {
  __shared__ float shmem[8192];  // 32 KB union
  const int bid = blockIdx.x;
  const int t = threadIdx.x;

  if (bid < NB_BS) {
    // ---------------- bsplit (Wbig -> fp16 hi/lo B-frags) ----------------
    float* lds = shmem;
    const int kc = bid;
    if (kc < 64) {
      for (int r = t; r < 4096; r += 256) {
        float2 v = *(const float2*)&nn2_w[(size_t)r * 128 + kc * 2];
        lds[r * 2] = v.x;
        lds[r * 2 + 1] = v.y;
      }
    } else if (kc == 64) {
      for (int r = t; r < 4096; r += 256) {
        lds[r * 2] = nn2_b[r];
        lds[r * 2 + 1] = 0.f;
      }
    } else {
      for (int r = t; r < 4096; r += 256) {
        int i = r >> 6, o = r & 63;
        lds[r * 2] = root_w[o * 64 + i];
        lds[r * 2 + 1] = 0.f;
      }
    }
    __syncthreads();
    for (int slot = t; slot < 1024; slot += 256) {
      int lane = slot & 63, c = (slot >> 6) & 3, w = slot >> 8;
      f16x8 ph, pl;
#pragma unroll
      for (int j = 0; j < 8; ++j) {
        int mm = w * 32 + ((lane >> 4) << 3) + j;
        int o = c * 16 + (lane & 15);
        int i = mm & 63, kl = mm >> 6;
        float v = lds[(i * 64 + o) * 2 + kl];
        _Float16 h = (_Float16)v;
        ph[j] = h;
        pl[j] = (_Float16)(v - (float)h);
      }
      size_t base = (((size_t)kc * 4 + w) * 4 + c) * 512 + (size_t)lane * 8;
      *(f16x8*)&Bh[base] = ph;
      *(f16x8*)&Bl[base] = pl;
    }
  } else if (bid < NB_BS + NB_GS) {
    // ---------------- gsplit (GRU weights -> 128x256 B-frags) ------------
    const int c = bid - NB_BS;
    const int w = t >> 6, lane = t & 63;
    const int part = c >> 2, dblk = c & 3;
    f16x8 oh, ol;
#pragma unroll
    for (int j = 0; j < 8; ++j) {
      int k = w * 32 + ((lane >> 4) << 3) + j;
      int d = dblk * 16 + (lane & 15);
      float v;
      if (part == 0) {
        v = (k < 64) ? gw_ih[(size_t)d * 64 + k]
                     : gw_hh[(size_t)d * 64 + (k - 64)];
      } else if (part == 1) {
        v = (k < 64) ? gw_ih[(size_t)(64 + d) * 64 + k]
                     : gw_hh[(size_t)(64 + d) * 64 + (k - 64)];
      } else if (part == 2) {
        v = (k < 64) ? gw_ih[(size_t)(128 + d) * 64 + k] : 0.f;
      } else {
        v = (k >= 64) ? gw_hh[(size_t)(128 + d) * 64 + (k - 64)] : 0.f;
      }
      _Float16 h = (_Float16)v;
      oh[j] = h;
      ol[j] = (_Float16)(v - (float)h);
    }
    size_t base = ((size_t)(w * 16 + c) * 64 + lane) * 8;
    *(f16x8*)&Gh[base] = oh;
    *(f16x8*)&Gl[base] = ol;
  } else if (bid < NB_BS + NB_GS + NB_H1) {
    // ---------------- h1t (edge MLP -> paired fp16 h chunks) -------------
    float* w5 = shmem;           // 640
    float* bb = shmem + 640;     // 128
    float* at = shmem + 768;     // 128*10
    float* idg = shmem + 2048;   // 128
    float* vf1 = shmem + 2176;   // 128
    const int m0 = (bid - NB_BS - NB_GS) * 128;
    const int MPtot = dptr2[N] >> 1;
    for (int idx = t; idx < 640; idx += 256) w5[idx] = nn1_w[idx];
    if (t < 128) bb[t] = nn1_b[t];
    if (t < 128) {
      int m = m0 + t;
      int e0 = (m < MPtot) ? eord[2 * m] : -1;
      int e1 = (m < MPtot) ? eord[2 * m + 1] : -1;
      float iv = 0.f, vf = 0.f;
      if (e0 >= 0) {
        const float* a = eattr + (size_t)e0 * 5;
#pragma unroll
        for (int q = 0; q < 5; ++q) at[t * 10 + q] = a[q];
        int dg = cnt[eidx[E + e0]];
        iv = 1.f / (float)(dg > 1 ? dg : 1);
        if (e1 >= 0) {
          const float* b = eattr + (size_t)e1 * 5;
#pragma unroll
          for (int q = 0; q < 5; ++q) at[t * 10 + 5 + q] = b[q];
          vf = 1.f;
        } else {
#pragma unroll
          for (int q = 0; q < 5; ++q) at[t * 10 + 5 + q] = 0.f;
        }
      } else {
#pragma unroll
        for (int q = 0; q < 10; ++q) at[t * 10 + q] = 0.f;
      }
      idg[t] = iv;
      vf1[t] = vf;
    }
    __syncthreads();
    const int pl = t & 127, jh = (t >> 7) * 64;
    const int m = m0 + pl;
    float a0 = at[pl * 10 + 0], a1 = at[pl * 10 + 1], a2 = at[pl * 10 + 2],
          a3 = at[pl * 10 + 3], a4 = at[pl * 10 + 4];
    float b0 = at[pl * 10 + 5], b1 = at[pl * 10 + 6], b2 = at[pl * 10 + 7],
          b3 = at[pl * 10 + 8], b4 = at[pl * 10 + 9];
    float iv = idg[pl], vf = vf1[pl];
#pragma unroll 4
    for (int ci = 0; ci < 16; ++ci) {
      int j0 = jh + ci * 4;
      f16x8 o;
#pragma unroll
      for (int u = 0; u < 4; ++u) {
        const float* wr = &w5[(j0 + u) * 5];
        float v0 = fmaxf(bb[j0 + u] + a0 * wr[0] + a1 * wr[1] + a2 * wr[2] +
                             a3 * wr[3] + a4 * wr[4], 0.f) * iv;
        float v1 = fmaxf(bb[j0 + u] + b0 * wr[0] + b1 * wr[1] + b2 * wr[2] +
                             b3 * wr[3] + b4 * wr[4], 0.f) * iv * vf;
        o[2 * u] = (_Float16)v0;
        o[2 * u + 1] = (_Float16)v1;
      }
      hp[(size_t)(j0 >> 2) * PAIRS_CAP + m] = o;
    }
  } else {
    // ---------------- lin0: out = relu(x @ lin0_w^T + lin0_b) ------------
    int gid = (bid - NB_BS - NB_GS - NB_H1) * 256 + t;
    int n = gid >> 6, d = gid & 63;
    if (n >= N) return;
    const float* xr = x + (size_t)n * 11;
    const float* wr = lin0_w + d * 11;
    float acc = lin0_b[d];
#pragma unroll
    for (int f = 0; f < 11; ++f) acc += xr[f] * wr[f];
    outn[(size_t)n * 64 + d] = fmaxf(acc, 0.f);
  }
}

// -- fused NNConv: 512 thr / 8 waves, dot2 build, LDS wq-reduce, no atomics -
//    extra iterations: split1 = bias (ph0 only), split2 = root (ph1 only)
__global__ __launch_bounds__(512, 4) void k_fused(
    const float* __restrict__ outn, const f16x8* __restrict__ hp,
    const int* __restrict__ dptr2, const int* __restrict__ cnt,
    const int* __restrict__ srcs_s, const _Float16* __restrict__ Bh,
    const _Float16* __restrict__ Bl, float* __restrict__ agg2, int N) {
  __shared__ __align__(16) _Float16 Ah[32 * 64 * 8];  // 32 KB (both sub-chunks)
  __shared__ uint4 sbufq[PMAX * 17];                  // 40.4 KB paired rows
  __shared__ uint4 hpq[2][PMAX];                      // 4.75 KB h-pair dbuf

  const int t = threadIdx.x;
  const int w = t >> 6, lane = t & 63;
  const int wq = w & 3;            // K-slice (B row-block)
  const int c_off = (w >> 2) * 2;  // C column half
  const int nl = t >> 3;           // builder node (0..63)
  const int io = t & 7;            // i-octant (8 cols)
  const int split = blockIdx.y;
  const int n0 = blockIdx.x * 64;
  const int n = n0 + nl;
  const bool nvalid = (n < N);
  const int hi_n = (n0 + 64 > N) ? N : (n0 + 64);
  const int p0b = dptr2[n0];
  const int p1b = dptr2[hi_n];
  const int MP0 = p0b >> 1;
  const int MPn = (p1b - p0b) >> 1;
  const bool useLds = (MPn <= PMAX);
  int mp0 = 0, mp1 = 0, deg = 0;
  if (nvalid) { mp0 = dptr2[n] >> 1; mp1 = dptr2[n + 1] >> 1; deg = cnt[n]; }
  const float inv = 1.f / (float)(deg > 1 ? deg : 1);
  const int odd = deg & 1;
  const int rt_b = nl >> 4, nm = nl & 15;
  const int MPs = useLds ? MPn : 0;

  // ---- stage paired src rows (interleaved half2) + first h-pair chunk ----
  for (int idx = t; idx < MPs * 16; idx += 512) {
    int ml = idx >> 4, g = idx & 15;
    int e0s = srcs_s[2 * (MP0 + ml)];
    int e1s = srcs_s[2 * (MP0 + ml) + 1];
    float4 r0 = *(const float4*)(outn + (size_t)e0s * 64 + g * 4);
    float4 r1 = *(const float4*)(outn + (size_t)e1s * 64 + g * 4);
    f16x8 o;
    o[0] = (_Float16)r0.x; o[1] = (_Float16)r1.x;
    o[2] = (_Float16)r0.y; o[3] = (_Float16)r1.y;
    o[4] = (_Float16)r0.z; o[5] = (_Float16)r1.z;
    o[6] = (_Float16)r0.w; o[7] = (_Float16)r1.w;
    sbufq[ml * 17 + (((g >> 2) ^ (ml & 3)) << 2) + (g & 3)] =
        __builtin_bit_cast(uint4, o);
  }
  for (int idx = t; idx < MPs; idx += 512)
    hpq[0][idx] =
        *(const uint4*)&hp[(size_t)(split * ITERS) * PAIRS_CAP + MP0 + idx];
  __syncthreads();

  f32x4 acc[4][2];
#pragma unroll
  for (int a = 0; a < 4; ++a)
#pragma unroll
    for (int c = 0; c < 2; ++c) acc[a][c] = (f32x4)(0.f);

  const int niter = (split == 1 || split == 2) ? (ITERS + 1) : ITERS;
  int cur = 0;
  for (int cc = 0; cc < niter; ++cc) {
    const bool extra = (cc == ITERS);  // split1: bias; split2: root

    // ---- build: av[4 kl][8 i] via dot2 over this node's pairs ----
    float av[4][8];
#pragma unroll
    for (int kl = 0; kl < 4; ++kl)
#pragma unroll
      for (int j = 0; j < 8; ++j) av[kl][j] = 0.f;

    if (!extra) {
      if (useLds) {
        for (int m = mp0; m < mp1; ++m) {
          int ml = m - MP0;
          uint4 hu = hpq[cur][ml];
          h2 h0 = __builtin_bit_cast(h2, hu.x);
          h2 h1 = __builtin_bit_cast(h2, hu.y);
          h2 hh2 = __builtin_bit_cast(h2, hu.z);
          h2 h3 = __builtin_bit_cast(h2, hu.w);
          int sb = ml * 17 + (((io >> 1) ^ (ml & 3)) << 2) + (io & 1) * 2;
          uint4 su0 = sbufq[sb], su1 = sbufq[sb + 1];
          unsigned vs[8] = {su0.x, su0.y, su0.z, su0.w,
                            su1.x, su1.y, su1.z, su1.w};
#pragma unroll
          for (int v = 0; v < 8; ++v) {
            h2 sp = __builtin_bit_cast(h2, vs[v]);
            av[0][v] = FDOT2(h0, sp, av[0][v]);
            av[1][v] = FDOT2(h1, sp, av[1][v]);
            av[2][v] = FDOT2(hh2, sp, av[2][v]);
            av[3][v] = FDOT2(h3, sp, av[3][v]);
          }
        }
      } else {  // rare fallback: gather from global (fp32 rows, fp16 h pairs)
        const f16x8* hc = hp + (size_t)(split * ITERS + cc) * PAIRS_CAP;
        for (int m = mp0; m < mp1; ++m) {
          f16x8 hv = hc[m];
          int e0s = srcs_s[2 * m], e1s = srcs_s[2 * m + 1];
          const float4* pa = (const float4*)(outn + (size_t)e0s * 64 + io * 8);
          const float4* pb = (const float4*)(outn + (size_t)e1s * 64 + io * 8);
          float4 a0 = pa[0], a1 = pa[1];
          float4 c0 = pb[0], c1 = pb[1];
          float sv0[8] = {a0.x, a0.y, a0.z, a0.w, a1.x, a1.y, a1.z, a1.w};
          float sv1[8] = {c0.x, c0.y, c0.z, c0.w, c1.x, c1.y, c1.z, c1.w};
#pragma unroll
          for (int kl = 0; kl < 4; ++kl) {
            float hA = (float)hv[2 * kl], hB = (float)hv[2 * kl + 1];
#pragma unroll
            for (int j = 0; j < 8; ++j)
              av[kl][j] += hA * sv0[j] + hB * sv1[j];
          }
        }
      }
    } else if (split == 1) {
      // bias chunk (kc=64 -> av[0]): inv * sum over REAL edges of s
      if (useLds) {
        for (int m = mp0; m < mp1; ++m) {
          int ml = m - MP0;
          h2 msk;
          msk[0] = (_Float16)1.f;
          msk[1] = (_Float16)((odd && m == mp1 - 1) ? 0.f : 1.f);
          int sb = ml * 17 + (((io >> 1) ^ (ml & 3)) << 2) + (io & 1) * 2;
          uint4 su0 = sbufq[sb], su1 = sbufq[sb + 1];
          unsigned vs[8] = {su0.x, su0.y, su0.z, su0.w,
                            su1.x, su1.y, su1.z, su1.w};
#pragma unroll
          for (int v = 0; v < 8; ++v) {
            h2 sp = __builtin_bit_cast(h2, vs[v]);
            av[0][v] = FDOT2(msk, sp, av[0][v]);
          }
        }
      } else {
        for (int m = mp0; m < mp1; ++m) {
          float m1 = (odd && m == mp1 - 1) ? 0.f : 1.f;
          int e0s = srcs_s[2 * m], e1s = srcs_s[2 * m + 1];
          const float4* pa = (const float4*)(outn + (size_t)e0s * 64 + io * 8);
          const float4* pb = (const float4*)(outn + (size_t)e1s * 64 + io * 8);
          float4 a0 = pa[0], a1 = pa[1];
          float4 c0 = pb[0], c1 = pb[1];
          float sv0[8] = {a0.x, a0.y, a0.z, a0.w, a1.x, a1.y, a1.z, a1.w};
          float sv1[8] = {c0.x, c0.y, c0.z, c0.w, c1.x, c1.y, c1.z, c1.w};
#pragma unroll
          for (int j = 0; j < 8; ++j) av[0][j] += sv0[j] + m1 * sv1[j];
        }
      }
#pragma unroll
      for (int j = 0; j < 8; ++j) av[0][j] *= inv;
    } else {
      // root chunk (kc=65 -> av[2]): A[n] = outn[n]
      if (nvalid) {
        const float4* sp = (const float4*)(outn + (size_t)n * 64 + io * 8);
        float4 s0 = sp[0], s1 = sp[1];
        float sv[8] = {s0.x, s0.y, s0.z, s0.w, s1.x, s1.y, s1.z, s1.w};
#pragma unroll
        for (int j = 0; j < 8; ++j) av[2][j] = sv[j];
      }
    }

    // ---- write ALL 4 kl A-frags (fp16, one f16x8 per kl), one barrier ----
#pragma unroll
    for (int kl = 0; kl < 4; ++kl) {
      const int wb = (kl & 1) * 2 + (io >> 2);
      const int q = ((io >> 1) & 1) * 2 + (io & 1);
      const int fb = (kl >> 1) * 16 + wb * 4 + rt_b;
      const int base = (fb * 64 + (q << 4) + nm) * 8;
      f16x8 phv;
#pragma unroll
      for (int jj = 0; jj < 8; ++jj) phv[jj] = (_Float16)av[kl][jj];
      *(f16x8*)&Ah[base] = phv;
    }
    __syncthreads();

    // ---- MFMA sub-chunks (extra: split1 ph0 only / split2 ph1 only) ----
    const int phA = (extra && split == 2) ? 1 : 0;
    const int phB = (extra && split == 1) ? 1 : 2;
    for (int ph = phA; ph < phB; ++ph) {
      const int kco = extra ? (64 + ph) : (split * 16 + cc * 2 + ph);
      f16x8 ah[4];
#pragma unroll
      for (int rt = 0; rt < 4; ++rt)
        ah[rt] = *(const f16x8*)&Ah[((ph * 16 + wq * 4 + rt) * 64 + lane) * 8];
      if (ph == phA && t < 256 && cc + 1 < ITERS) {
        const uint4* hc =
            (const uint4*)&hp[(size_t)(split * ITERS + cc + 1) * PAIRS_CAP + MP0];
        for (int idx = t; idx < MPs; idx += 256) hpq[cur ^ 1][idx] = hc[idx];
      }
      size_t bbase = ((size_t)(kco * 4 + wq) * 4) * 512;
#pragma unroll
      for (int c2 = 0; c2 < 2; ++c2) {
        const int c = c_off + c2;
        f16x8 bh = *(const f16x8*)&Bh[bbase + c * 512 + lane * 8];
        f16x8 bl = *(const f16x8*)&Bl[bbase + c * 512 + lane * 8];
#pragma unroll
        for (int rt = 0; rt < 4; ++rt) {
          acc[rt][c2] = __builtin_amdgcn_mfma_f32_16x16x32_f16(ah[rt], bh, acc[rt][c2], 0, 0, 0);
          acc[rt][c2] = __builtin_amdgcn_mfma_f32_16x16x32_f16(ah[rt], bl, acc[rt][c2], 0, 0, 0);
        }
      }
    }
    __syncthreads();
    if (cc + 1 < ITERS) cur ^= 1;
  }

  // ---- epilogue: cross-wq LDS reduction (no atomics), regular stores ----
  {
    float* redb = (float*)Ah;
    const int qrow = (lane >> 4) * 4, col15 = lane & 15;
    const int g14 = ((lane >> 4) & 1) << 4;
    if (wq == 1 || wq == 3) {
      float* L = redb + (wq >> 1) * 4096;
#pragma unroll
      for (int rt = 0; rt < 4; ++rt)
#pragma unroll
        for (int r = 0; r < 4; ++r) {
          int row = rt * 16 + qrow + r;
#pragma unroll
          for (int c2 = 0; c2 < 2; ++c2) {
            int col = (c_off + c2) * 16 + col15;
            L[row * 64 + (col ^ g14)] = acc[rt][c2][r];
          }
        }
    }
    __syncthreads();
    if (wq == 0 || wq == 2) {
      const float* L = redb + (wq >> 1) * 4096;
#pragma unroll
      for (int rt = 0; rt < 4; ++rt)
#pragma unroll
        for (int r = 0; r < 4; ++r) {
          int row = rt * 16 + qrow + r;
#pragma unroll
          for (int c2 = 0; c2 < 2; ++c2) {
            int col = (c_off + c2) * 16 + col15;
            acc[rt][c2][r] += L[row * 64 + (col ^ g14)];
          }
        }
    }
    __syncthreads();
    if (wq == 2) {
      float* L = redb;  // layer0 reuse
#pragma unroll
      for (int rt = 0; rt < 4; ++rt)
#pragma unroll
        for (int r = 0; r < 4; ++r) {
          int row = rt * 16 + qrow + r;
#pragma unroll
          for (int c2 = 0; c2 < 2; ++c2) {
            int col = (c_off + c2) * 16 + col15;
            L[row * 64 + (col ^ g14)] = acc[rt][c2][r];
          }
        }
    }
    __syncthreads();
    if (wq == 0) {
      const float* L = redb;
      float* ag = agg2 + (size_t)split * (size_t)N * 64;
#pragma unroll
      for (int rt = 0; rt < 4; ++rt)
#pragma unroll
        for (int r = 0; r < 4; ++r) {
          int row = rt * 16 + qrow + r;
          int nn = n0 + row;
          if (nn < N) {
#pragma unroll
            for (int c2 = 0; c2 < 2; ++c2) {
              int col = (c_off + c2) * 16 + col15;
              float v = acc[rt][c2][r] + L[row * 64 + (col ^ g14)];
              ag[(size_t)nn * 64 + col] = v;
            }
          }
        }
    }
  }
}

// MFMA GRU: 64 nodes/block, A=[m|h] fp16 frags, in-register gate epilogue.
__global__ __launch_bounds__(512) void k_gru2(
    const float* __restrict__ agg2, const float* __restrict__ conv_b,
    const _Float16* __restrict__ Gh, const _Float16* __restrict__ Gl,
    const float* __restrict__ gb_ih, const float* __restrict__ gb_hh,
    float* __restrict__ outn, int N) {
  __shared__ __align__(16) _Float16 Afrag[16 * 64 * 8];  // 16 KB
  __shared__ float bih[192], bhh[192];
  const int t = threadIdx.x;
  const int n0 = blockIdx.x * 64;
  const size_t NN = (size_t)N * 64;
  if (t < 192) { bih[t] = gb_ih[t]; bhh[t] = gb_hh[t]; }

  // ---- phase 1: build A = [m | h] (fp16) in MFMA A-frag order ----
  {
    const int nl = t >> 3, io = t & 7;
    const int n = n0 + nl;
    float v[16];
    if (n < N) {
      if (io < 4) {
        const int d0 = io * 16;
        const size_t base = (size_t)n * 64 + d0;
#pragma unroll
        for (int q = 0; q < 4; ++q) {
          float4 s0 = *(const float4*)&agg2[base + q * 4];
          float4 s1 = *(const float4*)&agg2[NN + base + q * 4];
          float4 s2 = *(const float4*)&agg2[2 * NN + base + q * 4];
          float4 s3 = *(const float4*)&agg2[3 * NN + base + q * 4];
          float4 cb = *(const float4*)&conv_b[d0 + q * 4];
          v[q * 4 + 0] = fmaxf(s0.x + s1.x + s2.x + s3.x + cb.x, 0.f);
          v[q * 4 + 1] = fmaxf(s0.y + s1.y + s2.y + s3.y + cb.y, 0.f);
          v[q * 4 + 2] = fmaxf(s0.z + s1.z + s2.z + s3.z + cb.z, 0.f);
          v[q * 4 + 3] = fmaxf(s0.w + s1.w + s2.w + s3.w + cb.w, 0.f);
        }
      } else {
        const int d0 = (io - 4) * 16;
#pragma unroll
        for (int q = 0; q < 4; ++q) {
          float4 h4 = *(const float4*)&outn[(size_t)n * 64 + d0 + q * 4];
          v[q * 4 + 0] = h4.x;
          v[q * 4 + 1] = h4.y;
          v[q * 4 + 2] = h4.z;
          v[q * 4 + 3] = h4.w;
        }
      }
    } else {
#pragma unroll
      for (int j = 0; j < 16; ++j) v[j] = 0.f;
    }
    const int rt = nl >> 4, m = nl & 15;
#pragma unroll
    for (int g2 = 0; g2 < 2; ++g2) {
      int k0 = io * 16 + g2 * 8;
      int ksub = k0 >> 5, kgrp = (k0 >> 3) & 3;
      f16x8 o;
#pragma unroll
      for (int jj = 0; jj < 8; ++jj) o[jj] = (_Float16)v[g2 * 8 + jj];
      *(f16x8*)&Afrag[((ksub * 4 + rt) * 64 + (kgrp << 4) + m) * 8] = o;
    }
  }
  __syncthreads();

  // ---- phase 2: MFMA with gate-part-aligned c-sets + in-register GRU ----
  const int w = t >> 6, lane = t & 63;
  const int rt = w >> 1, q2 = (w & 1) * 2;
  f32x4 acc[8];
#pragma unroll
  for (int i = 0; i < 8; ++i) acc[i] = (f32x4)(0.f);
#pragma unroll
  for (int ks = 0; ks < 4; ++ks) {
    f16x8 ah = *(const f16x8*)&Afrag[((ks * 4 + rt) * 64 + lane) * 8];
#pragma unroll
    for (int idx = 0; idx < 8; ++idx) {
      int c = (idx >> 1) * 4 + q2 + (idx & 1);
      f16x8 gh = *(const f16x8*)&Gh[((size_t)(ks * 16 + c) * 64 + lane) * 8];
      f16x8 gl = *(const f16x8*)&Gl[((size_t)(ks * 16 + c) * 64 + lane) * 8];
      acc[idx] = __builtin_amdgcn_mfma_f32_16x16x32_f16(ah, gh, acc[idx], 0, 0, 0);
      acc[idx] = __builtin_amdgcn_mfma_f32_16x16x32_f16(ah, gl, acc[idx], 0, 0, 0);
    }
  }
  const int qrow = (lane >> 4) * 4, col = lane & 15;
#pragma unroll
  for (int c01 = 0; c01 < 2; ++c01) {
    const int d = (q2 + c01) * 16 + col;
#pragma unroll
    for (int r = 0; r < 4; ++r) {
      const int n = n0 + rt * 16 + qrow + r;
      if (n < N) {
        float rs = acc[c01][r], zs = acc[2 + c01][r];
        float inn = acc[4 + c01][r], hn = acc[6 + c01][r];
        float h = outn[(size_t)n * 64 + d];
        float rg = 1.f / (1.f + expf(-(rs + bih[d] + bhh[d])));
        float zg = 1.f / (1.f + expf(-(zs + bih[64 + d] + bhh[64 + d])));
        float ng = tanhf(inn + bih[128 + d] + rg * (hn + bhh[128 + d]));
        outn[(size_t)n * 64 + d] = (1.f - zg) * ng + zg * h;
      }
    }
  }
}

// ---------------- fused Set2Set (3 steps) + readout, one block per graph ---
__global__ __launch_bounds__(256) void k_s2s(
    const float* __restrict__ outn, const int* __restrict__ gptr,
    const float* __restrict__ w_ih, const float* __restrict__ w_hh,
    const float* __restrict__ b_ih, const float* __restrict__ b_hh,
    const float* __restrict__ w1, const float* __restrict__ b1,
    const float* __restrict__ w2, const float* __restrict__ b2,
    float* __restrict__ y) {
  __shared__ float q[128];
  __shared__ float hsL[64];
  __shared__ float csL[64];
  __shared__ float gate[256];
  __shared__ float red[4][66];  // per-wave: m, den, racc[64]
  const int b = blockIdx.x, t = threadIdx.x;
  const int wv = t >> 6, d = t & 63;
  const int n0 = gptr[b], n1 = gptr[b + 1];
  if (t < 128) q[t] = 0.f;
  if (t < 64) { hsL[t] = 0.f; csL[t] = 0.f; }
  __syncthreads();

  for (int step = 0; step < 3; ++step) {
    // gates matvec with 4-way partial sums (break the serial FMA chain)
    float p0 = 0.f, p1 = 0.f, p2 = 0.f, p3 = 0.f;
    const float* wi = w_ih + t * 128;
    const float* wh = w_hh + t * 64;
    for (int k = 0; k < 128; k += 4) {
      p0 += wi[k] * q[k];
      p1 += wi[k + 1] * q[k + 1];
      p2 += wi[k + 2] * q[k + 2];
      p3 += wi[k + 3] * q[k + 3];
    }
    for (int k = 0; k < 64; k += 4) {
      p0 += wh[k] * hsL[k];
      p1 += wh[k + 1] * hsL[k + 1];
      p2 += wh[k + 2] * hsL[k + 2];
      p3 += wh[k + 3] * hsL[k + 3];
    }
    gate[t] = b_ih[t] + b_hh[t] + (p0 + p1) + (p2 + p3);
    __syncthreads();
    if (t < 64) {
      float ig = gate[t], fg = gate[64 + t], gg = gate[128 + t],
            og = gate[192 + t];
      float c = csL[t];
      float si = 1.f / (1.f + expf(-ig));
      float sf = 1.f / (1.f + expf(-fg));
      float so = 1.f / (1.f + expf(-og));
      float cn = sf * c + si * tanhf(gg);
      csL[t] = cn;
      hsL[t] = so * tanhf(cn);
    }
    __syncthreads();

    float qd = hsL[d];
    float mx = -3.4e38f, den = 0.f, racc = 0.f;
    for (int nn = n0 + wv; nn < n1; nn += 4) {
      float od = outn[(size_t)nn * 64 + d];
      float v = od * qd;
      for (int s = 32; s > 0; s >>= 1) v += __shfl_xor(v, s);
      float mnew = fmaxf(mx, v);
      float scale = expf(mx - mnew);
      float a = expf(v - mnew);
      den = den * scale + a;
      racc = racc * scale + a * od;
      mx = mnew;
    }
    if (d == 0) { red[wv][0] = mx; red[wv][1] = den; }
    red[wv][2 + d] = racc;
    __syncthreads();
    if (t < 64) {
      float M = fmaxf(fmaxf(red[0][0], red[1][0]), fmaxf(red[2][0], red[3][0]));
      float dd = 0.f, rr = 0.f;
#pragma unroll
      for (int ww = 0; ww < 4; ++ww) {
        float sc = expf(red[ww][0] - M);
        dd += red[ww][1] * sc;
        rr += red[ww][2 + t] * sc;
      }
      float r = (dd > 0.f) ? rr / dd : 0.f;
      q[t] = hsL[t];
      q[64 + t] = r;
    }
    __syncthreads();
  }

  if (t < 64) {
    float p0 = 0.f, p1 = 0.f, p2 = 0.f, p3 = 0.f;
    const float* wr = w1 + t * 128;
    for (int k = 0; k < 128; k += 4) {
      p0 += wr[k] * q[k];
      p1 += wr[k + 1] * q[k + 1];
      p2 += wr[k + 2] * q[k + 2];
      p3 += wr[k + 3] * q[k + 3];
    }
    float acc = b1[t] + (p0 + p1) + (p2 + p3);
    acc = fmaxf(acc, 0.f) * w2[t];
    for (int s = 32; s > 0; s >>= 1) acc += __shfl_xor(acc, s);
    if (t == 0) y[b] = acc + b2[0];
  }
}

extern "C" void kernel_launch(void* const* d_in, const int* in_sizes, int n_in,
                              void* d_out, int out_size, void* d_ws,
                              size_t ws_size, hipStream_t stream) {
  (void)n_in; (void)out_size; (void)ws_size;
  const float* x      = (const float*)d_in[0];
  const int*   eidx   = (const int*)d_in[1];
  const float* eattr  = (const float*)d_in[2];
  const int*   batch  = (const int*)d_in[3];
  const float* lin0_w = (const float*)d_in[4];
  const float* lin0_b = (const float*)d_in[5];
  const float* nn1_w  = (const float*)d_in[6];
  const float* nn1_b  = (const float*)d_in[7];
  const float* nn2_w  = (const float*)d_in[8];
  const float* nn2_b  = (const float*)d_in[9];
  const float* root_w = (const float*)d_in[10];
  const float* conv_b = (const float*)d_in[11];
  const float* gw_ih  = (const float*)d_in[12];
  const float* gw_hh  = (const float*)d_in[13];
  const float* gb_ih  = (const float*)d_in[14];
  const float* gb_hh  = (const float*)d_in[15];
  const float* lw_ih  = (const float*)d_in[16];
  const float* lw_hh  = (const float*)d_in[17];
  const float* lb_ih  = (const float*)d_in[18];
  const float* lb_hh  = (const float*)d_in[19];
  const float* lin1_w = (const float*)d_in[20];
  const float* lin1_b = (const float*)d_in[21];
  const float* lin2_w = (const float*)d_in[22];
  const float* lin2_b = (const float*)d_in[23];

  const int N = in_sizes[0] / 11;
  const int E = in_sizes[1] / 2;
  const int B = 512;

  size_t off = 0;
  auto bump = [&](size_t bytes) {
    size_t o = off;
    off += (bytes + 255) & ~(size_t)255;
    return o;
  };
  char* base = (char*)d_ws;
  float*     outn   = (float*)(base + bump((size_t)N * 64 * 4));
  float*     agg2   = (float*)(base + bump((size_t)SPLITK * N * 64 * 4));
  f16x8*     hpG    = (f16x8*)(base + bump((size_t)32 * PAIRS_CAP * 16));
  _Float16*  Bh     = (_Float16*)(base + bump((size_t)BFRAG_TOTAL * 2));
  _Float16*  Bl     = (_Float16*)(base + bump((size_t)BFRAG_TOTAL * 2));
  _Float16*  Gh     = (_Float16*)(base + bump((size_t)GFRAG_TOTAL * 2));
  _Float16*  Gl     = (_Float16*)(base + bump((size_t)GFRAG_TOTAL * 2));
  int*       cnt    = (int*)(base + bump((size_t)2 * N * 4));  // cnt + fill
  int*       fill   = cnt + N;
  int*       dptr2  = (int*)(base + bump((size_t)(N + 1) * 4));
  int*       srcs_s = (int*)(base + bump((size_t)2 * PAIRS_CAP * 4));
  int*       eord   = (int*)(base + bump((size_t)2 * PAIRS_CAP * 4));
  int*       gptr   = (int*)(base + bump((size_t)(B + 1) * 4));

  hipMemsetAsync(cnt, 0, (size_t)2 * N * 4, stream);

  const int gcGrid = ((N > E ? N : E) + 255) / 256;
  k_gc<<<gcGrid, 256, 0, stream>>>(batch, gptr, eidx, cnt, N, E, B);
  k_scan<<<1, 1024, 0, stream>>>(cnt, dptr2, N);
  k_fill<<<gcGrid, 256, 0, stream>>>(eidx, dptr2, cnt, fill, srcs_s, eord, E, N);

  const int NB_L0 = (N * 64 + 255) / 256;
  k_prep<<<NB_BS + NB_GS + NB_H1 + NB_L0, 256, 0, stream>>>(
      nn2_w, nn2_b, root_w, Bh, Bl, gw_ih, gw_hh, Gh, Gl, eattr, eord, eidx,
      cnt, dptr2, nn1_w, nn1_b, hpG, E, x, lin0_w, lin0_b, outn, N);

  const int NBLK = (N + 63) / 64;
  for (int it = 0; it < 3; ++it) {
    k_fused<<<dim3(NBLK, SPLITK), 512, 0, stream>>>(outn, hpG, dptr2, cnt,
                                                    srcs_s, Bh, Bl, agg2, N);
    k_gru2<<<NBLK, 512, 0, stream>>>(agg2, conv_b, Gh, Gl, gb_ih, gb_hh, outn,
                                     N);
  }

  k_s2s<<<B, 256, 0, stream>>>(outn, gptr, lw_ih, lw_hh, lb_ih, lb_hh, lin1_w,
                               lin1_b, lin2_w, lin2_b, (float*)d_out);
}

// Round 17
// 607.733 us; speedup vs baseline: 1.0765x; 1.0765x over previous
//
#include <hip/hip_runtime.h>
#include <math.h>

// ---------------------------------------------------------------------------
// MPNN (NNConv+GRU x3, Set2Set x3, readout).
// R27 = R25 restored (measured optimum, 608.0 us). R26's straggler
// rebalance REGRESSED (121->133 us k_fused): it doubled the extra-iteration
// block population and replaced the unrolled 2-phase MFMA loop with
// runtime bounds, deschedule-ing the hot path. Lever scorecard complete:
// work-cut null, TLP null, fewer-barriers spill, fewer-LDS-reads spill,
// co-residency negative, straggler negative. Latency-bound box between
// the 77 KB LDS floor and the 512-thr VGPR spill ceiling.
// ---------------------------------------------------------------------------

typedef _Float16 f16x8 __attribute__((ext_vector_type(8)));
typedef _Float16 h2 __attribute__((ext_vector_type(2)));
typedef float f32x4 __attribute__((ext_vector_type(4)));

#define BFRAG_TOTAL (66 * 4 * 4 * 64 * 8)  // 540672 halves per array
#define GFRAG_TOTAL (4 * 16 * 64 * 8)      // 32768 halves per array
#define PAIRS_CAP 40064                    // >= (E+N)/2, multiple of 128
#define PMAX 152                           // max pairs per 64-node block (LDS)
#define SPLITK 4
#define ITERS 8                            // 4-k chunks per split (32 k total)
#define NB_BS 66
#define NB_GS 16
#define NB_H1 (PAIRS_CAP / 128)            // 313

#if __has_builtin(__builtin_amdgcn_fdot2)
#define FDOT2(a, b, c) __builtin_amdgcn_fdot2((a), (b), (c), false)
#else
__device__ __forceinline__ float FDOT2(h2 a, h2 b, float c) {
  return c + (float)a[0] * (float)b[0] + (float)a[1] * (float)b[1];
}
#endif

// merged: graph segment pointers (from sorted batch) + degree count
__global__ void k_gc(const int* __restrict__ batch, int* __restrict__ gptr,
                     const int* __restrict__ eidx, int* __restrict__ cnt,
                     int N, int E, int B) {
  int i = blockIdx.x * 256 + threadIdx.x;
  if (i < N) {
    int b = batch[i];
    int bp = (i == 0) ? -1 : batch[i - 1];
    for (int g = bp + 1; g <= b; ++g) gptr[g] = i;
    if (i == N - 1) {
      for (int g = b + 1; g <= B; ++g) gptr[g] = N;
    }
  }
  if (i < E) atomicAdd(&cnt[eidx[E + i]], 1);
}

// segment-per-thread scan of EVEN-PADDED degrees -> dptr2 (2 barriers)
__global__ __launch_bounds__(1024) void k_scan(const int* __restrict__ cnt,
                                               int* __restrict__ dptr2, int N) {
  __shared__ int wsum[16];
  const int t = threadIdx.x, lane = t & 63, wid = t >> 6;
  const int per = (N + 1023) >> 10;
  int beg = t * per;
  int end = beg + per;
  if (beg > N) beg = N;
  if (end > N) end = N;
  int s = 0;
  for (int i = beg; i < end; ++i) s += (cnt[i] + 1) & ~1;
  int x = s;
#pragma unroll
  for (int d = 1; d < 64; d <<= 1) {
    int u = __shfl_up(x, d, 64);
    if (lane >= d) x += u;
  }
  if (lane == 63) wsum[wid] = x;
  __syncthreads();
  if (wid == 0) {
    int y = (lane < 16) ? wsum[lane] : 0;
#pragma unroll
    for (int d = 1; d < 16; d <<= 1) {
      int u = __shfl_up(y, d, 64);
      if (lane >= d) y += u;
    }
    if (lane < 16) wsum[lane] = y;
  }
  __syncthreads();
  int run = (x - s) + (wid > 0 ? wsum[wid - 1] : 0);  // exclusive prefix
  for (int i = beg; i < end; ++i) {
    run += (cnt[i] + 1) & ~1;
    dptr2[i + 1] = run;
  }
  if (t == 0) dptr2[0] = 0;
}

// fill CSR + write odd-degree pad slots (replaces srcs_s/eord memsets)
__global__ void k_fill(const int* __restrict__ eidx, const int* __restrict__ dptr2,
                       const int* __restrict__ cnt, int* __restrict__ fill,
                       int* __restrict__ srcs_s, int* __restrict__ eord, int E,
                       int N) {
  int i = blockIdx.x * 256 + threadIdx.x;
  if (i < E) {
    int d = eidx[E + i];
    int pos = dptr2[d] + atomicAdd(&fill[d], 1);
    srcs_s[pos] = eidx[i];
    eord[pos] = i;
  }
  if (i < N) {
    int dg = cnt[i];
    if (dg & 1) {
      int pos = dptr2[i] + dg;
      srcs_s[pos] = 0;
      eord[pos] = -1;
    }
  }
}

// ---- merged pre-pass: [0,NB_BS) bsplit | [..+NB_GS) gsplit |
//      [..+NB_H1) h1t | rest lin0 -----------------------------------------
__global__ __launch_bounds__(256) void k_prep(
    // bsplit
    const float* __restrict__ nn2_w, const float* __restrict__ nn2_b,
    const float* __restrict__ root_w, _Float16* __restrict__ Bh,
    _Float16* __restrict__ Bl,
    // gsplit
    const float* __restrict__ gw_ih, const float* __restrict__ gw_hh,
    _Float16* __restrict__ Gh, _Float16* __restrict__ Gl,
    // h1t
    const float* __restrict__ eattr, const int* __restrict__ eord,
    const int* __restrict__ eidx, const int* __restrict__ cnt,
    const int* __restrict__ dptr2, const float* __restrict__ nn1_w,
    const float* __restrict__ nn1_b, f16x8* __restrict__ hp, int E,
    // lin0
    const float* __restrict__ x, const float* __restrict__ lin0_w,
    const float* __restrict__ lin0_b, float* __restrict__ outn, int N) {
  __shared__ float shmem[8192];  // 32 KB union
  const int bid = blockIdx.x;
  const int t = threadIdx.x;

  if (bid < NB_BS) {
    // ---------------- bsplit (Wbig -> fp16 hi/lo B-frags) ----------------
    float* lds = shmem;
    const int kc = bid;
    if (kc < 64) {
      for (int r = t; r < 4096; r += 256) {
        float2 v = *(const float2*)&nn2_w[(size_t)r * 128 + kc * 2];
        lds[r * 2] = v.x;
        lds[r * 2 + 1] = v.y;
      }
    } else if (kc == 64) {
      for (int r = t; r < 4096; r += 256) {
        lds[r * 2] = nn2_b[r];
        lds[r * 2 + 1] = 0.f;
      }
    } else {
      for (int r = t; r < 4096; r += 256) {
        int i = r >> 6, o = r & 63;
        lds[r * 2] = root_w[o * 64 + i];
        lds[r * 2 + 1] = 0.f;
      }
    }
    __syncthreads();
    for (int slot = t; slot < 1024; slot += 256) {
      int lane = slot & 63, c = (slot >> 6) & 3, w = slot >> 8;
      f16x8 ph, pl;
#pragma unroll
      for (int j = 0; j < 8; ++j) {
        int mm = w * 32 + ((lane >> 4) << 3) + j;
        int o = c * 16 + (lane & 15);
        int i = mm & 63, kl = mm >> 6;
        float v = lds[(i * 64 + o) * 2 + kl];
        _Float16 h = (_Float16)v;
        ph[j] = h;
        pl[j] = (_Float16)(v - (float)h);
      }
      size_t base = (((size_t)kc * 4 + w) * 4 + c) * 512 + (size_t)lane * 8;
      *(f16x8*)&Bh[base] = ph;
      *(f16x8*)&Bl[base] = pl;
    }
  } else if (bid < NB_BS + NB_GS) {
    // ---------------- gsplit (GRU weights -> 128x256 B-frags) ------------
    const int c = bid - NB_BS;
    const int w = t >> 6, lane = t & 63;
    const int part = c >> 2, dblk = c & 3;
    f16x8 oh, ol;
#pragma unroll
    for (int j = 0; j < 8; ++j) {
      int k = w * 32 + ((lane >> 4) << 3) + j;
      int d = dblk * 16 + (lane & 15);
      float v;
      if (part == 0) {
        v = (k < 64) ? gw_ih[(size_t)d * 64 + k]
                     : gw_hh[(size_t)d * 64 + (k - 64)];
      } else if (part == 1) {
        v = (k < 64) ? gw_ih[(size_t)(64 + d) * 64 + k]
                     : gw_hh[(size_t)(64 + d) * 64 + (k - 64)];
      } else if (part == 2) {
        v = (k < 64) ? gw_ih[(size_t)(128 + d) * 64 + k] : 0.f;
      } else {
        v = (k >= 64) ? gw_hh[(size_t)(128 + d) * 64 + (k - 64)] : 0.f;
      }
      _Float16 h = (_Float16)v;
      oh[j] = h;
      ol[j] = (_Float16)(v - (float)h);
    }
    size_t base = ((size_t)(w * 16 + c) * 64 + lane) * 8;
    *(f16x8*)&Gh[base] = oh;
    *(f16x8*)&Gl[base] = ol;
  } else if (bid < NB_BS + NB_GS + NB_H1) {
    // ---------------- h1t (edge MLP -> paired fp16 h chunks) -------------
    float* w5 = shmem;           // 640
    float* bb = shmem + 640;     // 128
    float* at = shmem + 768;     // 128*10
    float* idg = shmem + 2048;   // 128
    float* vf1 = shmem + 2176;   // 128
    const int m0 = (bid - NB_BS - NB_GS) * 128;
    const int MPtot = dptr2[N] >> 1;
    for (int idx = t; idx < 640; idx += 256) w5[idx] = nn1_w[idx];
    if (t < 128) bb[t] = nn1_b[t];
    if (t < 128) {
      int m = m0 + t;
      int e0 = (m < MPtot) ? eord[2 * m] : -1;
      int e1 = (m < MPtot) ? eord[2 * m + 1] : -1;
      float iv = 0.f, vf = 0.f;
      if (e0 >= 0) {
        const float* a = eattr + (size_t)e0 * 5;
#pragma unroll
        for (int q = 0; q < 5; ++q) at[t * 10 + q] = a[q];
        int dg = cnt[eidx[E + e0]];
        iv = 1.f / (float)(dg > 1 ? dg : 1);
        if (e1 >= 0) {
          const float* b = eattr + (size_t)e1 * 5;
#pragma unroll
          for (int q = 0; q < 5; ++q) at[t * 10 + 5 + q] = b[q];
          vf = 1.f;
        } else {
#pragma unroll
          for (int q = 0; q < 5; ++q) at[t * 10 + 5 + q] = 0.f;
        }
      } else {
#pragma unroll
        for (int q = 0; q < 10; ++q) at[t * 10 + q] = 0.f;
      }
      idg[t] = iv;
      vf1[t] = vf;
    }
    __syncthreads();
    const int pl = t & 127, jh = (t >> 7) * 64;
    const int m = m0 + pl;
    float a0 = at[pl * 10 + 0], a1 = at[pl * 10 + 1], a2 = at[pl * 10 + 2],
          a3 = at[pl * 10 + 3], a4 = at[pl * 10 + 4];
    float b0 = at[pl * 10 + 5], b1 = at[pl * 10 + 6], b2 = at[pl * 10 + 7],
          b3 = at[pl * 10 + 8], b4 = at[pl * 10 + 9];
    float iv = idg[pl], vf = vf1[pl];
#pragma unroll 4
    for (int ci = 0; ci < 16; ++ci) {
      int j0 = jh + ci * 4;
      f16x8 o;
#pragma unroll
      for (int u = 0; u < 4; ++u) {
        const float* wr = &w5[(j0 + u) * 5];
        float v0 = fmaxf(bb[j0 + u] + a0 * wr[0] + a1 * wr[1] + a2 * wr[2] +
                             a3 * wr[3] + a4 * wr[4], 0.f) * iv;
        float v1 = fmaxf(bb[j0 + u] + b0 * wr[0] + b1 * wr[1] + b2 * wr[2] +
                             b3 * wr[3] + b4 * wr[4], 0.f) * iv * vf;
        o[2 * u] = (_Float16)v0;
        o[2 * u + 1] = (_Float16)v1;
      }
      hp[(size_t)(j0 >> 2) * PAIRS_CAP + m] = o;
    }
  } else {
    // ---------------- lin0: out = relu(x @ lin0_w^T + lin0_b) ------------
    int gid = (bid - NB_BS - NB_GS - NB_H1) * 256 + t;
    int n = gid >> 6, d = gid & 63;
    if (n >= N) return;
    const float* xr = x + (size_t)n * 11;
    const float* wr = lin0_w + d * 11;
    float acc = lin0_b[d];
#pragma unroll
    for (int f = 0; f < 11; ++f) acc += xr[f] * wr[f];
    outn[(size_t)n * 64 + d] = fmaxf(acc, 0.f);
  }
}

// -- fused NNConv: 512 thr / 8 waves, dot2 build, LDS wq-reduce, no atomics -
__global__ __launch_bounds__(512, 4) void k_fused(
    const float* __restrict__ outn, const f16x8* __restrict__ hp,
    const int* __restrict__ dptr2, const int* __restrict__ cnt,
    const int* __restrict__ srcs_s, const _Float16* __restrict__ Bh,
    const _Float16* __restrict__ Bl, float* __restrict__ agg2, int N) {
  __shared__ __align__(16) _Float16 Ah[32 * 64 * 8];  // 32 KB (both sub-chunks)
  __shared__ uint4 sbufq[PMAX * 17];                  // 40.4 KB paired rows
  __shared__ uint4 hpq[2][PMAX];                      // 4.75 KB h-pair dbuf

  const int t = threadIdx.x;
  const int w = t >> 6, lane = t & 63;
  const int wq = w & 3;            // K-slice (B row-block)
  const int c_off = (w >> 2) * 2;  // C column half
  const int nl = t >> 3;           // builder node (0..63)
  const int io = t & 7;            // i-octant (8 cols)
  const int split = blockIdx.y;
  const int n0 = blockIdx.x * 64;
  const int n = n0 + nl;
  const bool nvalid = (n < N);
  const int hi_n = (n0 + 64 > N) ? N : (n0 + 64);
  const int p0b = dptr2[n0];
  const int p1b = dptr2[hi_n];
  const int MP0 = p0b >> 1;
  const int MPn = (p1b - p0b) >> 1;
  const bool useLds = (MPn <= PMAX);
  int mp0 = 0, mp1 = 0, deg = 0;
  if (nvalid) { mp0 = dptr2[n] >> 1; mp1 = dptr2[n + 1] >> 1; deg = cnt[n]; }
  const float inv = 1.f / (float)(deg > 1 ? deg : 1);
  const int odd = deg & 1;
  const int rt_b = nl >> 4, nm = nl & 15;
  const int MPs = useLds ? MPn : 0;

  // ---- stage paired src rows (interleaved half2) + first h-pair chunk ----
  for (int idx = t; idx < MPs * 16; idx += 512) {
    int ml = idx >> 4, g = idx & 15;
    int e0s = srcs_s[2 * (MP0 + ml)];
    int e1s = srcs_s[2 * (MP0 + ml) + 1];
    float4 r0 = *(const float4*)(outn + (size_t)e0s * 64 + g * 4);
    float4 r1 = *(const float4*)(outn + (size_t)e1s * 64 + g * 4);
    f16x8 o;
    o[0] = (_Float16)r0.x; o[1] = (_Float16)r1.x;
    o[2] = (_Float16)r0.y; o[3] = (_Float16)r1.y;
    o[4] = (_Float16)r0.z; o[5] = (_Float16)r1.z;
    o[6] = (_Float16)r0.w; o[7] = (_Float16)r1.w;
    sbufq[ml * 17 + (((g >> 2) ^ (ml & 3)) << 2) + (g & 3)] =
        __builtin_bit_cast(uint4, o);
  }
  for (int idx = t; idx < MPs; idx += 512)
    hpq[0][idx] =
        *(const uint4*)&hp[(size_t)(split * ITERS) * PAIRS_CAP + MP0 + idx];
  __syncthreads();

  f32x4 acc[4][2];
#pragma unroll
  for (int a = 0; a < 4; ++a)
#pragma unroll
    for (int c = 0; c < 2; ++c) acc[a][c] = (f32x4)(0.f);

  const int niter = (split == 0) ? (ITERS + 1) : ITERS;
  int cur = 0;
  for (int cc = 0; cc < niter; ++cc) {
    const bool extra = (cc == ITERS);  // bias+root combined (split 0 only)

    // ---- build: av[4 kl][8 i] via dot2 over this node's pairs ----
    float av[4][8];
#pragma unroll
    for (int kl = 0; kl < 4; ++kl)
#pragma unroll
      for (int j = 0; j < 8; ++j) av[kl][j] = 0.f;

    if (!extra) {
      if (useLds) {
        for (int m = mp0; m < mp1; ++m) {
          int ml = m - MP0;
          uint4 hu = hpq[cur][ml];
          h2 h0 = __builtin_bit_cast(h2, hu.x);
          h2 h1 = __builtin_bit_cast(h2, hu.y);
          h2 hh2 = __builtin_bit_cast(h2, hu.z);
          h2 h3 = __builtin_bit_cast(h2, hu.w);
          int sb = ml * 17 + (((io >> 1) ^ (ml & 3)) << 2) + (io & 1) * 2;
          uint4 su0 = sbufq[sb], su1 = sbufq[sb + 1];
          unsigned vs[8] = {su0.x, su0.y, su0.z, su0.w,
                            su1.x, su1.y, su1.z, su1.w};
#pragma unroll
          for (int v = 0; v < 8; ++v) {
            h2 sp = __builtin_bit_cast(h2, vs[v]);
            av[0][v] = FDOT2(h0, sp, av[0][v]);
            av[1][v] = FDOT2(h1, sp, av[1][v]);
            av[2][v] = FDOT2(hh2, sp, av[2][v]);
            av[3][v] = FDOT2(h3, sp, av[3][v]);
          }
        }
      } else {  // rare fallback: gather from global (fp32 rows, fp16 h pairs)
        const f16x8* hc = hp + (size_t)(split * ITERS + cc) * PAIRS_CAP;
        for (int m = mp0; m < mp1; ++m) {
          f16x8 hv = hc[m];
          int e0s = srcs_s[2 * m], e1s = srcs_s[2 * m + 1];
          const float4* pa = (const float4*)(outn + (size_t)e0s * 64 + io * 8);
          const float4* pb = (const float4*)(outn + (size_t)e1s * 64 + io * 8);
          float4 a0 = pa[0], a1 = pa[1];
          float4 c0 = pb[0], c1 = pb[1];
          float sv0[8] = {a0.x, a0.y, a0.z, a0.w, a1.x, a1.y, a1.z, a1.w};
          float sv1[8] = {c0.x, c0.y, c0.z, c0.w, c1.x, c1.y, c1.z, c1.w};
#pragma unroll
          for (int kl = 0; kl < 4; ++kl) {
            float hA = (float)hv[2 * kl], hB = (float)hv[2 * kl + 1];
#pragma unroll
            for (int j = 0; j < 8; ++j)
              av[kl][j] += hA * sv0[j] + hB * sv1[j];
          }
        }
      }
    } else {
      // bias chunk (kc=64 -> av[0]): inv * sum over REAL edges of s
      if (useLds) {
        for (int m = mp0; m < mp1; ++m) {
          int ml = m - MP0;
          h2 msk;
          msk[0] = (_Float16)1.f;
          msk[1] = (_Float16)((odd && m == mp1 - 1) ? 0.f : 1.f);
          int sb = ml * 17 + (((io >> 1) ^ (ml & 3)) << 2) + (io & 1) * 2;
          uint4 su0 = sbufq[sb], su1 = sbufq[sb + 1];
          unsigned vs[8] = {su0.x, su0.y, su0.z, su0.w,
                            su1.x, su1.y, su1.z, su1.w};
#pragma unroll
          for (int v = 0; v < 8; ++v) {
            h2 sp = __builtin_bit_cast(h2, vs[v]);
            av[0][v] = FDOT2(msk, sp, av[0][v]);
          }
        }
      } else {
        for (int m = mp0; m < mp1; ++m) {
          float m1 = (odd && m == mp1 - 1) ? 0.f : 1.f;
          int e0s = srcs_s[2 * m], e1s = srcs_s[2 * m + 1];
          const float4* pa = (const float4*)(outn + (size_t)e0s * 64 + io * 8);
          const float4* pb = (const float4*)(outn + (size_t)e1s * 64 + io * 8);
          float4 a0 = pa[0], a1 = pa[1];
          float4 c0 = pb[0], c1 = pb[1];
          float sv0[8] = {a0.x, a0.y, a0.z, a0.w, a1.x, a1.y, a1.z, a1.w};
          float sv1[8] = {c0.x, c0.y, c0.z, c0.w, c1.x, c1.y, c1.z, c1.w};
#pragma unroll
          for (int j = 0; j < 8; ++j) av[0][j] += sv0[j] + m1 * sv1[j];
        }
      }
#pragma unroll
      for (int j = 0; j < 8; ++j) av[0][j] *= inv;
      // root chunk (kc=65 -> av[2]): A[n] = outn[n]
      if (nvalid) {
        const float4* sp = (const float4*)(outn + (size_t)n * 64 + io * 8);
        float4 s0 = sp[0], s1 = sp[1];
        float sv[8] = {s0.x, s0.y, s0.z, s0.w, s1.x, s1.y, s1.z, s1.w};
#pragma unroll
        for (int j = 0; j < 8; ++j) av[2][j] = sv[j];
      }
    }

    // ---- write ALL 4 kl A-frags (fp16, one f16x8 per kl), one barrier ----
#pragma unroll
    for (int kl = 0; kl < 4; ++kl) {
      const int wb = (kl & 1) * 2 + (io >> 2);
      const int q = ((io >> 1) & 1) * 2 + (io & 1);
      const int fb = (kl >> 1) * 16 + wb * 4 + rt_b;
      const int base = (fb * 64 + (q << 4) + nm) * 8;
      f16x8 phv;
#pragma unroll
      for (int jj = 0; jj < 8; ++jj) phv[jj] = (_Float16)av[kl][jj];
      *(f16x8*)&Ah[base] = phv;
    }
    __syncthreads();

    // ---- MFMA both K=128 sub-chunks + prefetch next h-pair chunk ----
#pragma unroll
    for (int ph = 0; ph < 2; ++ph) {
      const int kco = extra ? (64 + ph) : (split * 16 + cc * 2 + ph);
      f16x8 ah[4];
#pragma unroll
      for (int rt = 0; rt < 4; ++rt)
        ah[rt] = *(const f16x8*)&Ah[((ph * 16 + wq * 4 + rt) * 64 + lane) * 8];
      if (ph == 0 && t < 256 && cc + 1 < ITERS) {
        const uint4* hc =
            (const uint4*)&hp[(size_t)(split * ITERS + cc + 1) * PAIRS_CAP + MP0];
        for (int idx = t; idx < MPs; idx += 256) hpq[cur ^ 1][idx] = hc[idx];
      }
      size_t bbase = ((size_t)(kco * 4 + wq) * 4) * 512;
#pragma unroll
      for (int c2 = 0; c2 < 2; ++c2) {
        const int c = c_off + c2;
        f16x8 bh = *(const f16x8*)&Bh[bbase + c * 512 + lane * 8];
        f16x8 bl = *(const f16x8*)&Bl[bbase + c * 512 + lane * 8];
#pragma unroll
        for (int rt = 0; rt < 4; ++rt) {
          acc[rt][c2] = __builtin_amdgcn_mfma_f32_16x16x32_f16(ah[rt], bh, acc[rt][c2], 0, 0, 0);
          acc[rt][c2] = __builtin_amdgcn_mfma_f32_16x16x32_f16(ah[rt], bl, acc[rt][c2], 0, 0, 0);
        }
      }
    }
    __syncthreads();
    if (cc + 1 < ITERS) cur ^= 1;
  }

  // ---- epilogue: cross-wq LDS reduction (no atomics), regular stores ----
  {
    float* redb = (float*)Ah;
    const int qrow = (lane >> 4) * 4, col15 = lane & 15;
    const int g14 = ((lane >> 4) & 1) << 4;
    if (wq == 1 || wq == 3) {
      float* L = redb + (wq >> 1) * 4096;
#pragma unroll
      for (int rt = 0; rt < 4; ++rt)
#pragma unroll
        for (int r = 0; r < 4; ++r) {
          int row = rt * 16 + qrow + r;
#pragma unroll
          for (int c2 = 0; c2 < 2; ++c2) {
            int col = (c_off + c2) * 16 + col15;
            L[row * 64 + (col ^ g14)] = acc[rt][c2][r];
          }
        }
    }
    __syncthreads();
    if (wq == 0 || wq == 2) {
      const float* L = redb + (wq >> 1) * 4096;
#pragma unroll
      for (int rt = 0; rt < 4; ++rt)
#pragma unroll
        for (int r = 0; r < 4; ++r) {
          int row = rt * 16 + qrow + r;
#pragma unroll
          for (int c2 = 0; c2 < 2; ++c2) {
            int col = (c_off + c2) * 16 + col15;
            acc[rt][c2][r] += L[row * 64 + (col ^ g14)];
          }
        }
    }
    __syncthreads();
    if (wq == 2) {
      float* L = redb;  // layer0 reuse
#pragma unroll
      for (int rt = 0; rt < 4; ++rt)
#pragma unroll
        for (int r = 0; r < 4; ++r) {
          int row = rt * 16 + qrow + r;
#pragma unroll
          for (int c2 = 0; c2 < 2; ++c2) {
            int col = (c_off + c2) * 16 + col15;
            L[row * 64 + (col ^ g14)] = acc[rt][c2][r];
          }
        }
    }
    __syncthreads();
    if (wq == 0) {
      const float* L = redb;
      float* ag = agg2 + (size_t)split * (size_t)N * 64;
#pragma unroll
      for (int rt = 0; rt < 4; ++rt)
#pragma unroll
        for (int r = 0; r < 4; ++r) {
          int row = rt * 16 + qrow + r;
          int nn = n0 + row;
          if (nn < N) {
#pragma unroll
            for (int c2 = 0; c2 < 2; ++c2) {
              int col = (c_off + c2) * 16 + col15;
              float v = acc[rt][c2][r] + L[row * 64 + (col ^ g14)];
              ag[(size_t)nn * 64 + col] = v;
            }
          }
        }
    }
  }
}

// MFMA GRU: 64 nodes/block, A=[m|h] fp16 frags, in-register gate epilogue.
__global__ __launch_bounds__(512) void k_gru2(
    const float* __restrict__ agg2, const float* __restrict__ conv_b,
    const _Float16* __restrict__ Gh, const _Float16* __restrict__ Gl,
    const float* __restrict__ gb_ih, const float* __restrict__ gb_hh,
    float* __restrict__ outn, int N) {
  __shared__ __align__(16) _Float16 Afrag[16 * 64 * 8];  // 16 KB
  __shared__ float bih[192], bhh[192];
  const int t = threadIdx.x;
  const int n0 = blockIdx.x * 64;
  const size_t NN = (size_t)N * 64;
  if (t < 192) { bih[t] = gb_ih[t]; bhh[t] = gb_hh[t]; }

  // ---- phase 1: build A = [m | h] (fp16) in MFMA A-frag order ----
  {
    const int nl = t >> 3, io = t & 7;
    const int n = n0 + nl;
    float v[16];
    if (n < N) {
      if (io < 4) {
        const int d0 = io * 16;
        const size_t base = (size_t)n * 64 + d0;
#pragma unroll
        for (int q = 0; q < 4; ++q) {
          float4 s0 = *(const float4*)&agg2[base + q * 4];
          float4 s1 = *(const float4*)&agg2[NN + base + q * 4];
          float4 s2 = *(const float4*)&agg2[2 * NN + base + q * 4];
          float4 s3 = *(const float4*)&agg2[3 * NN + base + q * 4];
          float4 cb = *(const float4*)&conv_b[d0 + q * 4];
          v[q * 4 + 0] = fmaxf(s0.x + s1.x + s2.x + s3.x + cb.x, 0.f);
          v[q * 4 + 1] = fmaxf(s0.y + s1.y + s2.y + s3.y + cb.y, 0.f);
          v[q * 4 + 2] = fmaxf(s0.z + s1.z + s2.z + s3.z + cb.z, 0.f);
          v[q * 4 + 3] = fmaxf(s0.w + s1.w + s2.w + s3.w + cb.w, 0.f);
        }
      } else {
        const int d0 = (io - 4) * 16;
#pragma unroll
        for (int q = 0; q < 4; ++q) {
          float4 h4 = *(const float4*)&outn[(size_t)n * 64 + d0 + q * 4];
          v[q * 4 + 0] = h4.x;
          v[q * 4 + 1] = h4.y;
          v[q * 4 + 2] = h4.z;
          v[q * 4 + 3] = h4.w;
        }
      }
    } else {
#pragma unroll
      for (int j = 0; j < 16; ++j) v[j] = 0.f;
    }
    const int rt = nl >> 4, m = nl & 15;
#pragma unroll
    for (int g2 = 0; g2 < 2; ++g2) {
      int k0 = io * 16 + g2 * 8;
      int ksub = k0 >> 5, kgrp = (k0 >> 3) & 3;
      f16x8 o;
#pragma unroll
      for (int jj = 0; jj < 8; ++jj) o[jj] = (_Float16)v[g2 * 8 + jj];
      *(f16x8*)&Afrag[((ksub * 4 + rt) * 64 + (kgrp << 4) + m) * 8] = o;
    }
  }
  __syncthreads();

  // ---- phase 2: MFMA with gate-part-aligned c-sets + in-register GRU ----
  const int w = t >> 6, lane = t & 63;
  const int rt = w >> 1, q2 = (w & 1) * 2;
  f32x4 acc[8];
#pragma unroll
  for (int i = 0; i < 8; ++i) acc[i] = (f32x4)(0.f);
#pragma unroll
  for (int ks = 0; ks < 4; ++ks) {
    f16x8 ah = *(const f16x8*)&Afrag[((ks * 4 + rt) * 64 + lane) * 8];
#pragma unroll
    for (int idx = 0; idx < 8; ++idx) {
      int c = (idx >> 1) * 4 + q2 + (idx & 1);
      f16x8 gh = *(const f16x8*)&Gh[((size_t)(ks * 16 + c) * 64 + lane) * 8];
      f16x8 gl = *(const f16x8*)&Gl[((size_t)(ks * 16 + c) * 64 + lane) * 8];
      acc[idx] = __builtin_amdgcn_mfma_f32_16x16x32_f16(ah, gh, acc[idx], 0, 0, 0);
      acc[idx] = __builtin_amdgcn_mfma_f32_16x16x32_f16(ah, gl, acc[idx], 0, 0, 0);
    }
  }
  const int qrow = (lane >> 4) * 4, col = lane & 15;
#pragma unroll
  for (int c01 = 0; c01 < 2; ++c01) {
    const int d = (q2 + c01) * 16 + col;
#pragma unroll
    for (int r = 0; r < 4; ++r) {
      const int n = n0 + rt * 16 + qrow + r;
      if (n < N) {
        float rs = acc[c01][r], zs = acc[2 + c01][r];
        float inn = acc[4 + c01][r], hn = acc[6 + c01][r];
        float h = outn[(size_t)n * 64 + d];
        float rg = 1.f / (1.f + expf(-(rs + bih[d] + bhh[d])));
        float zg = 1.f / (1.f + expf(-(zs + bih[64 + d] + bhh[64 + d])));
        float ng = tanhf(inn + bih[128 + d] + rg * (hn + bhh[128 + d]));
        outn[(size_t)n * 64 + d] = (1.f - zg) * ng + zg * h;
      }
    }
  }
}

// ---------------- fused Set2Set (3 steps) + readout, one block per graph ---
__global__ __launch_bounds__(256) void k_s2s(
    const float* __restrict__ outn, const int* __restrict__ gptr,
    const float* __restrict__ w_ih, const float* __restrict__ w_hh,
    const float* __restrict__ b_ih, const float* __restrict__ b_hh,
    const float* __restrict__ w1, const float* __restrict__ b1,
    const float* __restrict__ w2, const float* __restrict__ b2,
    float* __restrict__ y) {
  __shared__ float q[128];
  __shared__ float hsL[64];
  __shared__ float csL[64];
  __shared__ float gate[256];
  __shared__ float red[4][66];  // per-wave: m, den, racc[64]
  const int b = blockIdx.x, t = threadIdx.x;
  const int wv = t >> 6, d = t & 63;
  const int n0 = gptr[b], n1 = gptr[b + 1];
  if (t < 128) q[t] = 0.f;
  if (t < 64) { hsL[t] = 0.f; csL[t] = 0.f; }
  __syncthreads();

  for (int step = 0; step < 3; ++step) {
    // gates matvec with 4-way partial sums (break the serial FMA chain)
    float p0 = 0.f, p1 = 0.f, p2 = 0.f, p3 = 0.f;
    const float* wi = w_ih + t * 128;
    const float* wh = w_hh + t * 64;
    for (int k = 0; k < 128; k += 4) {
      p0 += wi[k] * q[k];
      p1 += wi[k + 1] * q[k + 1];
      p2 += wi[k + 2] * q[k + 2];
      p3 += wi[k + 3] * q[k + 3];
    }
    for (int k = 0; k < 64; k += 4) {
      p0 += wh[k] * hsL[k];
      p1 += wh[k + 1] * hsL[k + 1];
      p2 += wh[k + 2] * hsL[k + 2];
      p3 += wh[k + 3] * hsL[k + 3];
    }
    gate[t] = b_ih[t] + b_hh[t] + (p0 + p1) + (p2 + p3);
    __syncthreads();
    if (t < 64) {
      float ig = gate[t], fg = gate[64 + t], gg = gate[128 + t],
            og = gate[192 + t];
      float c = csL[t];
      float si = 1.f / (1.f + expf(-ig));
      float sf = 1.f / (1.f + expf(-fg));
      float so = 1.f / (1.f + expf(-og));
      float cn = sf * c + si * tanhf(gg);
      csL[t] = cn;
      hsL[t] = so * tanhf(cn);
    }
    __syncthreads();

    float qd = hsL[d];
    float mx = -3.4e38f, den = 0.f, racc = 0.f;
    for (int nn = n0 + wv; nn < n1; nn += 4) {
      float od = outn[(size_t)nn * 64 + d];
      float v = od * qd;
      for (int s = 32; s > 0; s >>= 1) v += __shfl_xor(v, s);
      float mnew = fmaxf(mx, v);
      float scale = expf(mx - mnew);
      float a = expf(v - mnew);
      den = den * scale + a;
      racc = racc * scale + a * od;
      mx = mnew;
    }
    if (d == 0) { red[wv][0] = mx; red[wv][1] = den; }
    red[wv][2 + d] = racc;
    __syncthreads();
    if (t < 64) {
      float M = fmaxf(fmaxf(red[0][0], red[1][0]), fmaxf(red[2][0], red[3][0]));
      float dd = 0.f, rr = 0.f;
#pragma unroll
      for (int ww = 0; ww < 4; ++ww) {
        float sc = expf(red[ww][0] - M);
        dd += red[ww][1] * sc;
        rr += red[ww][2 + t] * sc;
      }
      float r = (dd > 0.f) ? rr / dd : 0.f;
      q[t] = hsL[t];
      q[64 + t] = r;
    }
    __syncthreads();
  }

  if (t < 64) {
    float p0 = 0.f, p1 = 0.f, p2 = 0.f, p3 = 0.f;
    const float* wr = w1 + t * 128;
    for (int k = 0; k < 128; k += 4) {
      p0 += wr[k] * q[k];
      p1 += wr[k + 1] * q[k + 1];
      p2 += wr[k + 2] * q[k + 2];
      p3 += wr[k + 3] * q[k + 3];
    }
    float acc = b1[t] + (p0 + p1) + (p2 + p3);
    acc = fmaxf(acc, 0.f) * w2[t];
    for (int s = 32; s > 0; s >>= 1) acc += __shfl_xor(acc, s);
    if (t == 0) y[b] = acc + b2[0];
  }
}

extern "C" void kernel_launch(void* const* d_in, const int* in_sizes, int n_in,
                              void* d_out, int out_size, void* d_ws,
                              size_t ws_size, hipStream_t stream) {
  (void)n_in; (void)out_size; (void)ws_size;
  const float* x      = (const float*)d_in[0];
  const int*   eidx   = (const int*)d_in[1];
  const float* eattr  = (const float*)d_in[2];
  const int*   batch  = (const int*)d_in[3];
  const float* lin0_w = (const float*)d_in[4];
  const float* lin0_b = (const float*)d_in[5];
  const float* nn1_w  = (const float*)d_in[6];
  const float* nn1_b  = (const float*)d_in[7];
  const float* nn2_w  = (const float*)d_in[8];
  const float* nn2_b  = (const float*)d_in[9];
  const float* root_w = (const float*)d_in[10];
  const float* conv_b = (const float*)d_in[11];
  const float* gw_ih  = (const float*)d_in[12];
  const float* gw_hh  = (const float*)d_in[13];
  const float* gb_ih  = (const float*)d_in[14];
  const float* gb_hh  = (const float*)d_in[15];
  const float* lw_ih  = (const float*)d_in[16];
  const float* lw_hh  = (const float*)d_in[17];
  const float* lb_ih  = (const float*)d_in[18];
  const float* lb_hh  = (const float*)d_in[19];
  const float* lin1_w = (const float*)d_in[20];
  const float* lin1_b = (const float*)d_in[21];
  const float* lin2_w = (const float*)d_in[22];
  const float* lin2_b = (const float*)d_in[23];

  const int N = in_sizes[0] / 11;
  const int E = in_sizes[1] / 2;
  const int B = 512;

  size_t off = 0;
  auto bump = [&](size_t bytes) {
    size_t o = off;
    off += (bytes + 255) & ~(size_t)255;
    return o;
  };
  char* base = (char*)d_ws;
  float*     outn   = (float*)(base + bump((size_t)N * 64 * 4));
  float*     agg2   = (float*)(base + bump((size_t)SPLITK * N * 64 * 4));
  f16x8*     hpG    = (f16x8*)(base + bump((size_t)32 * PAIRS_CAP * 16));
  _Float16*  Bh     = (_Float16*)(base + bump((size_t)BFRAG_TOTAL * 2));
  _Float16*  Bl     = (_Float16*)(base + bump((size_t)BFRAG_TOTAL * 2));
  _Float16*  Gh     = (_Float16*)(base + bump((size_t)GFRAG_TOTAL * 2));
  _Float16*  Gl     = (_Float16*)(base + bump((size_t)GFRAG_TOTAL * 2));
  int*       cnt    = (int*)(base + bump((size_t)2 * N * 4));  // cnt + fill
  int*       fill   = cnt + N;
  int*       dptr2  = (int*)(base + bump((size_t)(N + 1) * 4));
  int*       srcs_s = (int*)(base + bump((size_t)2 * PAIRS_CAP * 4));
  int*       eord   = (int*)(base + bump((size_t)2 * PAIRS_CAP * 4));
  int*       gptr   = (int*)(base + bump((size_t)(B + 1) * 4));

  hipMemsetAsync(cnt, 0, (size_t)2 * N * 4, stream);

  const int gcGrid = ((N > E ? N : E) + 255) / 256;
  k_gc<<<gcGrid, 256, 0, stream>>>(batch, gptr, eidx, cnt, N, E, B);
  k_scan<<<1, 1024, 0, stream>>>(cnt, dptr2, N);
  k_fill<<<gcGrid, 256, 0, stream>>>(eidx, dptr2, cnt, fill, srcs_s, eord, E, N);

  const int NB_L0 = (N * 64 + 255) / 256;
  k_prep<<<NB_BS + NB_GS + NB_H1 + NB_L0, 256, 0, stream>>>(
      nn2_w, nn2_b, root_w, Bh, Bl, gw_ih, gw_hh, Gh, Gl, eattr, eord, eidx,
      cnt, dptr2, nn1_w, nn1_b, hpG, E, x, lin0_w, lin0_b, outn, N);

  const int NBLK = (N + 63) / 64;
  for (int it = 0; it < 3; ++it) {
    k_fused<<<dim3(NBLK, SPLITK), 512, 0, stream>>>(outn, hpG, dptr2, cnt,
                                                    srcs_s, Bh, Bl, agg2, N);
    k_gru2<<<NBLK, 512, 0, stream>>>(agg2, conv_b, Gh, Gl, gb_ih, gb_hh, outn,
                                     N);
  }

  k_s2s<<<B, 256, 0, stream>>>(outn, gptr, lw_ih, lw_hh, lb_ih, lb_hh, lin1_w,
                               lin1_b, lin2_w, lin2_b, (float*)d_out);
}